// Round 1
// baseline (1174.699 us; speedup 1.0000x reference)
//
#include <hip/hip_runtime.h>
#include <math.h>

// Problem constants (SentenceDGConvNodeClassifier): N=20000, E=160000, D=768, H=256, C=10
// Outputs (fp32, concatenated): logits [N,10], node_features [N,513], edge_pairs [E,1026]

// ---------------- helpers ----------------

__global__ void k_hist(const int* __restrict__ dst, int* __restrict__ deg, int e) {
    int i = blockIdx.x * blockDim.x + threadIdx.x;
    if (i < e) atomicAdd(&deg[dst[i]], 1);
}

__global__ void k_dinv(const int* __restrict__ deg, float* __restrict__ dinv, int n) {
    int i = blockIdx.x * blockDim.x + threadIdx.x;
    if (i < n) dinv[i] = 1.0f / sqrtf((float)(deg[i] + 1));  // +1 self-loop; deg>=1 always
}

// single-block exclusive scan of deg[0..n) -> off[0..n], off[n]=total
__global__ __launch_bounds__(1024) void k_scan(const int* __restrict__ deg, int* __restrict__ off,
                                               int n, int total) {
    __shared__ int sm[1024];
    __shared__ int carry_s;
    if (threadIdx.x == 0) carry_s = 0;
    __syncthreads();
    for (int base = 0; base < n; base += 1024) {
        int i = base + threadIdx.x;
        int v = (i < n) ? deg[i] : 0;
        int x = v;
        sm[threadIdx.x] = x;
        __syncthreads();
        for (int ofs = 1; ofs < 1024; ofs <<= 1) {
            int add = (threadIdx.x >= ofs) ? sm[threadIdx.x - ofs] : 0;
            __syncthreads();
            x += add;
            sm[threadIdx.x] = x;
            __syncthreads();
        }
        if (i < n) off[i] = carry_s + x - v;  // exclusive
        __syncthreads();
        if (threadIdx.x == 1023) carry_s += sm[1023];
        __syncthreads();
    }
    if (threadIdx.x == 0) off[n] = total;
}

__global__ void k_scatter(const int* __restrict__ src, const int* __restrict__ dst,
                          const float* __restrict__ dinv, const int* __restrict__ off,
                          int* __restrict__ cursor, int* __restrict__ csr_src,
                          float* __restrict__ csr_w, int e) {
    int i = blockIdx.x * blockDim.x + threadIdx.x;
    if (i < e) {
        int d = dst[i], s = src[i];
        int pos = off[d] + atomicAdd(&cursor[d], 1);
        csr_src[pos] = s;
        csr_w[pos]   = dinv[s] * dinv[d];
    }
}

// ---------------- fp32 tiled GEMM: C[M,N] = A[M,K] @ B[K,N] ----------------
// BM=BN=64, BK=16, 256 threads, 4x4 accumulators per thread.
__global__ __launch_bounds__(256) void k_gemm(const float* __restrict__ A, int lda,
                                              const float* __restrict__ B, int ldb,
                                              float* __restrict__ C, int ldc,
                                              int M, int Nn, int K) {
    __shared__ float As[16][68];  // [k][m], pad 64->68 keeps 16B alignment, 2-way max conflict
    __shared__ float Bs[16][64];  // [k][n]

    const int tid = threadIdx.x;
    const int tx = tid & 15, ty = tid >> 4;
    const int m0 = blockIdx.y * 64, n0 = blockIdx.x * 64;
    const int kq = tid & 3, ar = tid >> 2;  // A-load: 64 rows x (4 float4 in k)

    float acc[4][4] = {};

    for (int k0 = 0; k0 < K; k0 += 16) {
        // stage next tiles into registers
        float4 av;
        const int arow = m0 + ar;
        if (arow < M) av = *(const float4*)(A + (size_t)arow * lda + k0 + kq * 4);
        else          av = make_float4(0.f, 0.f, 0.f, 0.f);
        const float4 bv = *(const float4*)(B + (size_t)(k0 + ty) * ldb + n0 + tx * 4);

        __syncthreads();  // protect previous iteration's reads
        As[kq * 4 + 0][ar] = av.x;
        As[kq * 4 + 1][ar] = av.y;
        As[kq * 4 + 2][ar] = av.z;
        As[kq * 4 + 3][ar] = av.w;
        *(float4*)&Bs[ty][tx * 4] = bv;
        __syncthreads();

#pragma unroll
        for (int kk = 0; kk < 16; kk++) {
            const float4 a = *(const float4*)&As[kk][ty * 4];
            const float4 b = *(const float4*)&Bs[kk][tx * 4];
            const float aa[4] = {a.x, a.y, a.z, a.w};
            const float bb[4] = {b.x, b.y, b.z, b.w};
#pragma unroll
            for (int i = 0; i < 4; i++)
#pragma unroll
                for (int j = 0; j < 4; j++) acc[i][j] += aa[i] * bb[j];
        }
    }

#pragma unroll
    for (int i = 0; i < 4; i++) {
        const int m = m0 + ty * 4 + i;
        if (m < M) {
            float4 o = {acc[i][0], acc[i][1], acc[i][2], acc[i][3]};
            *(float4*)(C + (size_t)m * ldc + n0 + tx * 4) = o;
        }
    }
}

// ---------------- aggregation (dim=256): h[v] = tanh(sum_nbr w*t[u] + dinv^2*t[v] + b) ----------------
__global__ __launch_bounds__(256) void k_aggregate(const float* __restrict__ t,
                                                   const float* __restrict__ bias,
                                                   const float* __restrict__ dinv,
                                                   const int* __restrict__ off,
                                                   const int* __restrict__ csr_src,
                                                   const float* __restrict__ csr_w,
                                                   float* __restrict__ hc,
                                                   float* __restrict__ nf, int col0) {
    const int v = blockIdx.x;
    const int d = threadIdx.x;
    const float di = dinv[v];
    float acc = di * di * t[(size_t)v * 256 + d];
    const int s_ = off[v], e_ = off[v + 1];
    for (int idx = s_; idx < e_; idx++) {
        const int u = csr_src[idx];
        const float w = csr_w[idx];
        acc += w * t[(size_t)u * 256 + d];
    }
    const float r = tanhf(acc + bias[d]);
    hc[(size_t)v * 256 + d] = r;
    nf[(size_t)v * 513 + col0 + d] = r;
}

// ---------------- layer3: s[v] = dot(hc[v,:256], W2) ----------------
__global__ __launch_bounds__(256) void k_rowdot(const float* __restrict__ hc,
                                                const float* __restrict__ W2,
                                                float* __restrict__ s, int n) {
    const int v = blockIdx.x * 4 + (threadIdx.x >> 6);
    const int lane = threadIdx.x & 63;
    if (v >= n) return;
    float p = 0.f;
    for (int k = lane; k < 256; k += 64) p += hc[(size_t)v * 256 + k] * W2[k];
    for (int ofs = 32; ofs > 0; ofs >>= 1) p += __shfl_down(p, ofs, 64);
    if (lane == 0) s[v] = p;
}

__global__ void k_agg_scalar(const float* __restrict__ s, const float* __restrict__ b2,
                             const float* __restrict__ dinv, const int* __restrict__ off,
                             const int* __restrict__ csr_src, const float* __restrict__ csr_w,
                             float* __restrict__ nf, int n) {
    const int v = blockIdx.x * blockDim.x + threadIdx.x;
    if (v >= n) return;
    const float di = dinv[v];
    float acc = di * di * s[v];
    const int e_ = off[v + 1];
    for (int idx = off[v]; idx < e_; idx++) acc += csr_w[idx] * s[csr_src[idx]];
    nf[(size_t)v * 513 + 512] = tanhf(acc + b2[0]);
}

// ---------------- classifier: logits[v] = nf[v] @ Wc + bc (wave per node) ----------------
__global__ __launch_bounds__(256) void k_classifier(const float* __restrict__ nf,
                                                    const float* __restrict__ Wc,
                                                    const float* __restrict__ bc,
                                                    float* __restrict__ logits, int n) {
    const int v = blockIdx.x * 4 + (threadIdx.x >> 6);
    const int lane = threadIdx.x & 63;
    if (v >= n) return;
    float p[10] = {};
    for (int k = lane; k < 513; k += 64) {
        const float x = nf[(size_t)v * 513 + k];
#pragma unroll
        for (int c = 0; c < 10; c++) p[c] += x * Wc[k * 10 + c];
    }
#pragma unroll
    for (int c = 0; c < 10; c++) {
        float q = p[c];
        for (int ofs = 32; ofs > 0; ofs >>= 1) q += __shfl_down(q, ofs, 64);
        if (lane == 0) logits[(size_t)v * 10 + c] = q + bc[c];
    }
}

// ---------------- edge pair gather: out[e] = [nf[src[e]], nf[dst[e]]] ----------------
__global__ __launch_bounds__(256) void k_edge_pairs(const float* __restrict__ nf,
                                                    const int* __restrict__ src,
                                                    const int* __restrict__ dst,
                                                    float* __restrict__ out, int e) {
    const int eid = blockIdx.x;
    const int si = src[eid], ti = dst[eid];
    const float* __restrict__ srow = nf + (size_t)si * 513;
    const float* __restrict__ trow = nf + (size_t)ti * 513;
    float* __restrict__ orow = out + (size_t)eid * 1026;
    for (int j = threadIdx.x; j < 1026; j += 256) {
        orow[j] = (j < 513) ? srow[j] : trow[j - 513];
    }
}

extern "C" void kernel_launch(void* const* d_in, const int* in_sizes, int n_in,
                              void* d_out, int out_size, void* d_ws, size_t ws_size,
                              hipStream_t stream) {
    const float* x  = (const float*)d_in[0];
    const int*   ei = (const int*)d_in[1];
    const float* W0 = (const float*)d_in[2];
    const float* b0 = (const float*)d_in[3];
    const float* W1 = (const float*)d_in[4];
    const float* b1 = (const float*)d_in[5];
    const float* W2 = (const float*)d_in[6];
    const float* b2 = (const float*)d_in[7];
    const float* Wc = (const float*)d_in[8];
    const float* bc = (const float*)d_in[9];

    const int n = in_sizes[0] / 768;   // 20000
    const int e = in_sizes[1] / 2;     // 160000
    const int* src  = ei;
    const int* dstp = ei + e;

    float* out    = (float*)d_out;
    float* logits = out;
    float* nf     = out + (size_t)n * 10;
    float* pairs  = nf + (size_t)n * 513;

    // workspace carve-up (all re-poisoned each call; everything below is written before read)
    char* w = (char*)d_ws;
    auto alloc = [&](size_t bytes) { char* p = w; w += (bytes + 255) & ~(size_t)255; return p; };
    int*   deg     = (int*)alloc((size_t)n * 4);
    int*   off     = (int*)alloc((size_t)(n + 1) * 4);
    int*   cursor  = (int*)alloc((size_t)n * 4);
    int*   csr_src = (int*)alloc((size_t)e * 4);
    float* csr_w   = (float*)alloc((size_t)e * 4);
    float* dinv    = (float*)alloc((size_t)n * 4);
    float* t       = (float*)alloc((size_t)n * 256 * 4);
    float* hc      = (float*)alloc((size_t)n * 256 * 4);
    float* sv      = (float*)alloc((size_t)n * 4);

    hipMemsetAsync(deg, 0, (size_t)n * 4, stream);
    hipMemsetAsync(cursor, 0, (size_t)n * 4, stream);

    // degree / norm / CSR build
    k_hist<<<(e + 255) / 256, 256, 0, stream>>>(dstp, deg, e);
    k_dinv<<<(n + 255) / 256, 256, 0, stream>>>(deg, dinv, n);
    k_scan<<<1, 1024, 0, stream>>>(deg, off, n, e);
    k_scatter<<<(e + 255) / 256, 256, 0, stream>>>(src, dstp, dinv, off, cursor, csr_src, csr_w, e);

    const int mblocks = (n + 63) / 64;

    // layer 1: t = x @ W0 ; h1 = tanh(agg(t) + b0)
    k_gemm<<<dim3(256 / 64, mblocks), 256, 0, stream>>>(x, 768, W0, 256, t, 256, n, 256, 768);
    k_aggregate<<<n, 256, 0, stream>>>(t, b0, dinv, off, csr_src, csr_w, hc, nf, 0);

    // layer 2: t = h1 @ W1 ; h2 = tanh(agg(t) + b1)
    k_gemm<<<dim3(256 / 64, mblocks), 256, 0, stream>>>(hc, 256, W1, 256, t, 256, n, 256, 256);
    k_aggregate<<<n, 256, 0, stream>>>(t, b1, dinv, off, csr_src, csr_w, hc, nf, 256);

    // layer 3: s = h2 @ W2 ; h3 = tanh(agg(s) + b2) -> nf col 512
    k_rowdot<<<(n + 3) / 4, 256, 0, stream>>>(hc, W2, sv, n);
    k_agg_scalar<<<(n + 255) / 256, 256, 0, stream>>>(sv, b2, dinv, off, csr_src, csr_w, nf, n);

    // classifier (reads full nf incl. col 512)
    k_classifier<<<(n + 3) / 4, 256, 0, stream>>>(nf, Wc, bc, logits, n);

    // edge pair features
    k_edge_pairs<<<e, 256, 0, stream>>>(nf, src, dstp, pairs, e);
}